// Round 4
// baseline (384.289 us; speedup 1.0000x reference)
//
#include <hip/hip_runtime.h>
#include <hip/hip_bf16.h>

// DotProductNonLocalBlock: B=8, C=512, N=3136 (pad 3200 for xT), E=256.
// Gram-matrix form (no softmax => fully associative):
//   G  = X·X^T                  [bf16 MFMA, split-K=7, atomic fp32 accumulate]
//   KV = Wk·G·Wv^T + (Wk s)bv^T + bk(Wv s)^T + N·bk·bv^T   (s = X·1)
//   W2 = wo·KV^T/N ; A2 = W2·wq ; a2 = W2·bq + bo          [small fp32]
//   Out = A2·X + a2 + X          [bf16 MFMA, 64x128 tiles, fp32 residual]
// All MFMA GEMMs use 64x128 tiles / 4 waves to maximize resident blocks
// (round-3 lesson: these GEMMs are occupancy/latency-bound, not conflict-bound).

typedef __attribute__((ext_vector_type(8))) __bf16 bf16x8;
typedef __attribute__((ext_vector_type(4))) float floatx4;

struct __align__(8) bh4 { __hip_bfloat16 x, y, z, w; };

__device__ __forceinline__ void load_lds16(const void* g, void* l) {
    __builtin_amdgcn_global_load_lds((const __attribute__((address_space(1))) void*)g,
                                     (__attribute__((address_space(3))) void*)l, 16, 0, 0);
}

__global__ void zero_f4(float4* __restrict__ p, int n4) {
    int i = blockIdx.x * 256 + threadIdx.x;
    if (i < n4) p[i] = make_float4(0.f, 0.f, 0.f, 0.f);
}

// x [b][512][3136] fp32 -> xT [b][3200][512] bf16 (pad rows zero)
//                        + xn [b][512][3136] bf16
//                        + s[b][c] += rowsums (atomic)
__global__ __launch_bounds__(256)
void transpose_conv(const float* __restrict__ x, __hip_bfloat16* __restrict__ xT,
                    __hip_bfloat16* __restrict__ xn, float* __restrict__ s)
{
    __shared__ float t[64][65];
    const int b = blockIdx.z;
    const int n0 = blockIdx.x * 64, c0 = blockIdx.y * 64;
    const int tx = threadIdx.x & 15, ty = threadIdx.x >> 4;
    __hip_bfloat16* xo = xT + (long long)b * 3200 * 512;
    const __hip_bfloat16 z = __float2bfloat16(0.f);
    if (n0 >= 3136) {   // pad tile
#pragma unroll
        for (int r = 0; r < 4; ++r) {
            bh4 zz = {z, z, z, z};
            *(bh4*)&xo[(long long)(n0 + ty + 16 * r) * 512 + c0 + tx * 4] = zz;
        }
        return;
    }
    const float* xb = x + (long long)b * 512 * 3136;
    __hip_bfloat16* xnb = xn + (long long)b * 512 * 3136;
    float rs[4];
#pragma unroll
    for (int r = 0; r < 4; ++r) {
        const long long off = (long long)(c0 + ty + 16 * r) * 3136 + n0 + tx * 4;
        float4 v = *(const float4*)&xb[off];
        t[tx * 4 + 0][ty + 16 * r] = v.x;
        t[tx * 4 + 1][ty + 16 * r] = v.y;
        t[tx * 4 + 2][ty + 16 * r] = v.z;
        t[tx * 4 + 3][ty + 16 * r] = v.w;
        bh4 o = {__float2bfloat16(v.x), __float2bfloat16(v.y),
                 __float2bfloat16(v.z), __float2bfloat16(v.w)};
        *(bh4*)&xnb[off] = o;
        rs[r] = v.x + v.y + v.z + v.w;
    }
#pragma unroll
    for (int r = 0; r < 4; ++r) {
#pragma unroll
        for (int m = 1; m < 16; m <<= 1) rs[r] += __shfl_xor(rs[r], m, 16);
    }
    if (tx == 0) {
#pragma unroll
        for (int r = 0; r < 4; ++r)
            atomicAdd(&s[b * 512 + c0 + ty + 16 * r], rs[r]);
    }
    __syncthreads();
#pragma unroll
    for (int r = 0; r < 4; ++r) {
        int nn = ty + 16 * r;
        bh4 o;
        o.x = __float2bfloat16(t[nn][tx * 4 + 0]);
        o.y = __float2bfloat16(t[nn][tx * 4 + 1]);
        o.z = __float2bfloat16(t[nn][tx * 4 + 2]);
        o.w = __float2bfloat16(t[nn][tx * 4 + 3]);
        *(bh4*)&xo[(long long)(n0 + nn) * 512 + c0 + tx * 4] = o;
    }
}

__global__ __launch_bounds__(256)
void cvt_bf16_4(const float4* __restrict__ src, bh4* __restrict__ dst, int n4)
{
    int i = blockIdx.x * 256 + threadIdx.x;
    if (i < n4) {
        float4 v = src[i];
        bh4 o = {__float2bfloat16(v.x), __float2bfloat16(v.y),
                 __float2bfloat16(v.z), __float2bfloat16(v.w)};
        dst[i] = o;
    }
}

// MFMA GEMM, both operands K-contiguous: C[m][n] = sum_k A[m][k]*B[n][k].
// 64(M)x128(N) tile, 4 waves (each 64x32: 4x2 frags), 16x16x32 MFMAs, template BK.
// MODE 1: fp32 atomicAdd into C (split-K accumulate).
// MODE 2: fp32 out = acc + bias[b][m] + xres[b][m][n], store only n<Nreal.
// LDS read swizzle keeps ds_read_b128 at <=2-way bank aliasing (free per m136):
//   BK=64: xor chunk by row&7 ; BK=32: xor by (row>>1)&3.
template<int MODE, int BKT>
__global__ __launch_bounds__(256)
void mfma64(const __hip_bfloat16* __restrict__ A, long long sA, int lda,
            const __hip_bfloat16* __restrict__ B, long long sB, int ldb,
            float* __restrict__ C, long long sC, int ldc,
            const float* __restrict__ bias, int sBias,
            const float* __restrict__ xres, long long sX,
            int kLen, int nSplit, int Nreal)
{
    constexpr int CPR = BKT / 8;        // 16B chunks per row
    constexpr int NA = 64 * CPR / 256;  // A chunks per thread (1 or 2)
    constexpr int NB = 128 * CPR / 256; // B chunks per thread (2 or 4)
    __shared__ __hip_bfloat16 As[64 * BKT];
    __shared__ __hip_bfloat16 Bs[128 * BKT];
    const int tid = threadIdx.x;
    const int lane = tid & 63;
    const int w = tid >> 6;             // wave: n-offset w*32
    const int ln = lane & 15;
    const int hi = lane >> 4;
    const int bz = blockIdx.z;
    const int batch = bz / nSplit;
    const int ks = bz - batch * nSplit;
    const int m0 = blockIdx.y << 6;
    const int n0 = blockIdx.x << 7;
    const long long k0 = (long long)ks * kLen;

#define SWZ(row) ((BKT == 64) ? ((row) & 7) : (((row) >> 1) & 3))

    const __hip_bfloat16* gA[NA];
    const __hip_bfloat16* gB[NB];
#pragma unroll
    for (int p = 0; p < NA; ++p) {
        int q = tid + 256 * p;
        int row = q / CPR;
        int c = (q % CPR) ^ SWZ(row);
        gA[p] = A + batch * sA + (long long)(m0 + row) * lda + k0 + c * 8;
    }
#pragma unroll
    for (int p = 0; p < NB; ++p) {
        int q = tid + 256 * p;
        int row = q / CPR;
        int c = (q % CPR) ^ SWZ(row);
        gB[p] = B + batch * sB + (long long)(n0 + row) * ldb + k0 + c * 8;
    }

    floatx4 acc[4][2] = {};

    const int nK = kLen / BKT;
    for (int kt = 0; kt < nK; ++kt) {
#pragma unroll
        for (int p = 0; p < NA; ++p) {
            load_lds16(gA[p], As + (tid + 256 * p) * 8);
            gA[p] += BKT;
        }
#pragma unroll
        for (int p = 0; p < NB; ++p) {
            load_lds16(gB[p], Bs + (tid + 256 * p) * 8);
            gB[p] += BKT;
        }
        __syncthreads();
#pragma unroll
        for (int kk = 0; kk < BKT / 32; ++kk) {
            const int cidx = kk * 4 + hi;
            bf16x8 af[4], bfr[2];
#pragma unroll
            for (int i = 0; i < 4; ++i) {
                int row = i * 16 + ln;
                af[i] = *(const bf16x8*)(As + row * BKT + ((cidx ^ SWZ(row)) << 3));
            }
#pragma unroll
            for (int j = 0; j < 2; ++j) {
                int row = w * 32 + j * 16 + ln;
                bfr[j] = *(const bf16x8*)(Bs + row * BKT + ((cidx ^ SWZ(row)) << 3));
            }
#pragma unroll
            for (int i = 0; i < 4; ++i)
#pragma unroll
                for (int j = 0; j < 2; ++j)
                    acc[i][j] = __builtin_amdgcn_mfma_f32_16x16x32_bf16(af[i], bfr[j], acc[i][j], 0, 0, 0);
        }
        __syncthreads();
    }
#undef SWZ

    // C/D layout: col = lane&15, row = (lane>>4)*4 + r  [m89-verified]
    if (MODE == 1) {
        float* Cb = C + batch * sC;
#pragma unroll
        for (int i = 0; i < 4; ++i) {
            int mb = m0 + i * 16 + hi * 4;
#pragma unroll
            for (int j = 0; j < 2; ++j) {
                int nl = n0 + w * 32 + j * 16 + ln;
#pragma unroll
                for (int r = 0; r < 4; ++r)
                    atomicAdd(&Cb[(long long)(mb + r) * ldc + nl], acc[i][j][r]);
            }
        }
    } else {
        float* Cb = C + batch * sC;
        const float* xb = xres + batch * sX;
#pragma unroll
        for (int i = 0; i < 4; ++i) {
            int mb = m0 + i * 16 + hi * 4;
#pragma unroll
            for (int r = 0; r < 4; ++r) {
                float bb = bias[batch * sBias + mb + r];
#pragma unroll
                for (int j = 0; j < 2; ++j) {
                    int nl = n0 + w * 32 + j * 16 + ln;
                    if (nl < Nreal) {
                        long long off = (long long)(mb + r) * ldc + nl;
                        Cb[off] = acc[i][j][r] + bb + xb[off];
                    }
                }
            }
        }
    }
}

// ks[b][e] = wk[e]·s[b], vs[b][e] = wv[e]·s[b]
__global__ __launch_bounds__(256)
void ksvs_kernel(const float* __restrict__ wk, const float* __restrict__ wv,
                 const float* __restrict__ s, float* __restrict__ ks, float* __restrict__ vs)
{
    int idx = blockIdx.x * 256 + threadIdx.x;   // 0..2047 = b*256 + e
    int b = idx >> 8, e = idx & 255;
    const float4* sv = (const float4*)(s + b * 512);
    const float4* k4 = (const float4*)(wk + (long long)e * 512);
    const float4* v4 = (const float4*)(wv + (long long)e * 512);
    float ak = 0.f, av = 0.f;
#pragma unroll 4
    for (int c = 0; c < 128; ++c) {
        float4 sc = sv[c], kk = k4[c], vv = v4[c];
        ak = fmaf(kk.x, sc.x, ak); ak = fmaf(kk.y, sc.y, ak);
        ak = fmaf(kk.z, sc.z, ak); ak = fmaf(kk.w, sc.w, ak);
        av = fmaf(vv.x, sc.x, av); av = fmaf(vv.y, sc.y, av);
        av = fmaf(vv.z, sc.z, av); av = fmaf(vv.w, sc.w, av);
    }
    ks[idx] = ak; vs[idx] = av;
}

// KV += ks·bv^T + bk·vs^T + N·bk·bv^T
__global__ __launch_bounds__(256)
void fixup_kernel(float* __restrict__ KV, const float* __restrict__ ks,
                  const float* __restrict__ vs, const float* __restrict__ bk,
                  const float* __restrict__ bv)
{
    int idx = blockIdx.x * 256 + threadIdx.x;   // b*65536 + i*256 + j
    int b = idx >> 16, ij = idx & 65535;
    int i = ij >> 8, j = ij & 255;
    KV[idx] += ks[b * 256 + i] * bv[j] + bk[i] * vs[b * 256 + j] + 3136.f * bk[i] * bv[j];
}

// ---- fp32 64x64 GEMM (round-1, verified) for the small steps ----
#define TILE 64
#define BK16 16
#define LDSP (TILE + 4)

template<bool BT>
__global__ __launch_bounds__(256)
void gemm64(const float* __restrict__ A, long long sA, int lda,
            const float* __restrict__ B, long long sB, int ldb,
            float* __restrict__ C, long long sC, int ldc,
            float alpha, int kLen)
{
    __shared__ __align__(16) float As[BK16][LDSP];
    __shared__ __align__(16) float Bs[BK16][LDSP];
    const int tid = threadIdx.x;
    const int tx = tid & 15, ty = tid >> 4;
    const int batch = blockIdx.z;
    const int m0 = blockIdx.y * TILE, n0 = blockIdx.x * TILE;
    const float* Ab = A + (long long)batch * sA;
    const float* Bb = B + (long long)batch * sB;
    float acc[4][4];
#pragma unroll
    for (int i = 0; i < 4; ++i)
#pragma unroll
        for (int j = 0; j < 4; ++j) acc[i][j] = 0.f;
    const int lr = tid >> 2, lk4 = (tid & 3) << 2;
    const int bk_ = tid >> 4, bn4 = (tid & 15) << 2;
    for (int k0 = 0; k0 < kLen; k0 += BK16) {
        float4 av = *(const float4*)&Ab[(long long)(m0 + lr) * lda + k0 + lk4];
        float4 bv;
        if (BT) bv = *(const float4*)&Bb[(long long)(n0 + lr) * ldb + k0 + lk4];
        else    bv = *(const float4*)&Bb[(long long)(k0 + bk_) * ldb + n0 + bn4];
        __syncthreads();
        As[lk4 + 0][lr] = av.x; As[lk4 + 1][lr] = av.y;
        As[lk4 + 2][lr] = av.z; As[lk4 + 3][lr] = av.w;
        if (BT) {
            Bs[lk4 + 0][lr] = bv.x; Bs[lk4 + 1][lr] = bv.y;
            Bs[lk4 + 2][lr] = bv.z; Bs[lk4 + 3][lr] = bv.w;
        } else {
            *(float4*)&Bs[bk_][bn4] = bv;
        }
        __syncthreads();
#pragma unroll
        for (int kk = 0; kk < BK16; ++kk) {
            float4 a4 = *(const float4*)&As[kk][ty << 2];
            float4 b4 = *(const float4*)&Bs[kk][tx << 2];
            const float a[4] = {a4.x, a4.y, a4.z, a4.w};
            const float b[4] = {b4.x, b4.y, b4.z, b4.w};
#pragma unroll
            for (int i = 0; i < 4; ++i)
#pragma unroll
                for (int j = 0; j < 4; ++j)
                    acc[i][j] = fmaf(a[i], b[j], acc[i][j]);
        }
    }
    const int mo = m0 + (ty << 2), no = n0 + (tx << 2);
    float* Cb = C + (long long)batch * sC;
#pragma unroll
    for (int i = 0; i < 4; ++i) {
        float4 v;
        v.x = acc[i][0] * alpha; v.y = acc[i][1] * alpha;
        v.z = acc[i][2] * alpha; v.w = acc[i][3] * alpha;
        *(float4*)&Cb[(long long)(mo + i) * ldc + no] = v;
    }
}

__global__ __launch_bounds__(256)
void a2_kernel(const float* __restrict__ W2, const float* __restrict__ bq,
               const float* __restrict__ bo, float* __restrict__ a2)
{
    int idx = blockIdx.x * 256 + threadIdx.x;   // b*512 + c
    int c = idx & 511;
    const float4* row = (const float4*)(W2 + (long long)idx * 256);
    const float4* q4 = (const float4*)bq;
    float s = 0.f;
#pragma unroll 4
    for (int e = 0; e < 64; ++e) {
        float4 w = row[e], b = q4[e];
        s = fmaf(w.x, b.x, s); s = fmaf(w.y, b.y, s);
        s = fmaf(w.z, b.z, s); s = fmaf(w.w, b.w, s);
    }
    a2[idx] = s + bo[c];
}

extern "C" void kernel_launch(void* const* d_in, const int* in_sizes, int n_in,
                              void* d_out, int out_size, void* d_ws, size_t ws_size,
                              hipStream_t stream)
{
    const float* x  = (const float*)d_in[0];
    const float* wq = (const float*)d_in[1];
    const float* bq = (const float*)d_in[2];
    const float* wk = (const float*)d_in[3];
    const float* bk = (const float*)d_in[4];
    const float* wv = (const float*)d_in[5];
    const float* bv = (const float*)d_in[6];
    const float* wo = (const float*)d_in[7];
    const float* bo = (const float*)d_in[8];
    float* out = (float*)d_out;

    const int C = 512, E = 256, N = 3136;
    const long long xs = (long long)C * N;   // 1,605,632

    // d_out scratch (51,380,224 B), liveness-overlapped, dead before final write:
    char* ob = (char*)d_out;
    __hip_bfloat16* xn = (__hip_bfloat16*)ob;          // @0        25,690,112 (dead after G)
    float* G   = (float*)(ob + 25690112);              //  8,388,608 (dead after T1)
    float* T1  = (float*)(ob + 0);                     //  4,194,304 over dead xn
    float* KV  = (float*)(ob + 4194304);               //  2,097,152
    float* W2  = (float*)(ob + 6291456);               //  4,194,304
    float* A2  = (float*)(ob + 10485760);              //  8,388,608 (ends 18.9MB < 25.7)

    // ws (~30.5 MB, proven budget)
    char* wsb = (char*)d_ws;
    __hip_bfloat16* xT  = (__hip_bfloat16*)wsb;                // 26,214,400
    __hip_bfloat16* A2b = (__hip_bfloat16*)(wsb + 26214400);   //  4,194,304
    float* sv  = (float*)(wsb + 30408704);                     //     16,384
    float* ksv = (float*)(wsb + 30425088);                     //      8,192
    float* vsv = (float*)(wsb + 30433280);                     //      8,192
    float* a2v = (float*)(wsb + 30441472);                     //     16,384

    // 0) zero atomic accumulators: s and G
    zero_f4<<<4, 256, 0, stream>>>((float4*)sv, 1024);
    zero_f4<<<2048, 256, 0, stream>>>((float4*)G, 2097152 / 4);

    // 1) xT (bf16, padded-transposed) + xn (bf16) + s (rowsums)
    transpose_conv<<<dim3(50, 8, 8), 256, 0, stream>>>(x, xT, xn, sv);

    // 2) G += xn·xn^T   split-K=7 (K=448, 14 iters), 1792 blocks = 7/CU
    mfma64<1, 32><<<dim3(4, 8, 56), 256, 0, stream>>>(
        xn, xs, N, xn, xs, N, G, (long long)C * C, C,
        nullptr, 0, nullptr, 0, 448, 7, C);

    // 3) ks = Wk·s, vs = Wv·s
    ksvs_kernel<<<8, 256, 0, stream>>>(wk, wv, sv, ksv, vsv);

    // 4) T1 = G·Wv^T   (M=512, N=256, K=512)
    gemm64<true><<<dim3(4, 8, 8), 256, 0, stream>>>(
        G, (long long)C * C, C, wv, 0, C, T1, (long long)C * E, E, 1.f, C);

    // 5) KV = Wk·T1    (M=256, N=256, K=512)
    gemm64<false><<<dim3(4, 4, 8), 256, 0, stream>>>(
        wk, 0, C, T1, (long long)C * E, E, KV, (long long)E * E, E, 1.f, C);

    // 6) KV += rank-1 bias terms
    fixup_kernel<<<2048, 256, 0, stream>>>(KV, ksv, vsv, bk, bv);

    // 7) W2 = wo·KV^T / N   (M=512, N=256, K=256)
    gemm64<true><<<dim3(4, 8, 8), 256, 0, stream>>>(
        wo, 0, E, KV, (long long)E * E, E, W2, (long long)C * E, E, 1.f / (float)N, E);

    // 8) A2 = W2·wq   (M=512, N=512, K=256)
    gemm64<false><<<dim3(8, 8, 8), 256, 0, stream>>>(
        W2, (long long)C * E, E, wq, 0, C, A2, (long long)C * C, C, 1.f, E);

    // 9) a2 = W2·bq + bo
    a2_kernel<<<16, 256, 0, stream>>>(W2, bq, bo, a2v);

    // 10) A2 -> bf16
    cvt_bf16_4<<<2048, 256, 0, stream>>>((const float4*)A2, (bh4*)A2b, 524288);

    // 11) out = A2b·X + a2 + x   (M=512, N=3136, K=512, BK=64), 1600 blocks
    mfma64<2, 64><<<dim3(25, 8, 8), 256, 0, stream>>>(
        A2b, (long long)C * C, C, xT, 3200LL * C, C,
        out, xs, N, a2v, C, x, xs, 512, 1, N);
}

// Round 5
// 310.446 us; speedup vs baseline: 1.2379x; 1.2379x over previous
//
#include <hip/hip_runtime.h>
#include <hip/hip_bf16.h>

// DotProductNonLocalBlock: B=8, C=512, N=3136 (pad 3200 for xT), E=256.
// No softmax => fully associative. Factored form with DATA-INDEPENDENT
// P = wo·wv, Qt = wq^T·wk, u = wo·bv, r = bk^T·wq, w = Wk^T·bq, κ = bk·bq:
//   G  = X·X^T (symmetric)      [bf16 MFMA, split-K=2, bf16 partials interleaved]
//   T  = P·G  (= Pd·Gp2, K=1024 folds the split-K reduce)   [bf16 MFMA]
//   A2 = [T·Q + u·(Qt s)^T + (P s)·r^T]/N + u·r^T            [bf16 MFMA + epilogue]
//   a2 = [T·w + u·(s·w) + (P s)·κ]/N + u·κ + bo              [tiny matvec]
//   Out = A2·X + a2 + X          [bf16 MFMA, 64x128 tiles, fp32 residual]

typedef __attribute__((ext_vector_type(8))) __bf16 bf16x8;
typedef __attribute__((ext_vector_type(4))) float floatx4;

struct __align__(8) bh4 { __hip_bfloat16 x, y, z, w; };

__device__ __forceinline__ void load_lds16(const void* g, void* l) {
    __builtin_amdgcn_global_load_lds((const __attribute__((address_space(1))) void*)g,
                                     (__attribute__((address_space(3))) void*)l, 16, 0, 0);
}

__global__ void zero_f4(float4* __restrict__ p, int n4) {
    int i = blockIdx.x * 256 + threadIdx.x;
    if (i < n4) p[i] = make_float4(0.f, 0.f, 0.f, 0.f);
}

// x [b][512][3136] fp32 -> xT [b][3200][512] bf16 (pad rows zero)
//                        + xn [b][512][3136] bf16
//                        + s[b][c] += rowsums (atomic)
__global__ __launch_bounds__(256)
void transpose_conv(const float* __restrict__ x, __hip_bfloat16* __restrict__ xT,
                    __hip_bfloat16* __restrict__ xn, float* __restrict__ s)
{
    __shared__ float t[64][65];
    const int b = blockIdx.z;
    const int n0 = blockIdx.x * 64, c0 = blockIdx.y * 64;
    const int tx = threadIdx.x & 15, ty = threadIdx.x >> 4;
    __hip_bfloat16* xo = xT + (long long)b * 3200 * 512;
    const __hip_bfloat16 z = __float2bfloat16(0.f);
    if (n0 >= 3136) {   // pad tile
#pragma unroll
        for (int r = 0; r < 4; ++r) {
            bh4 zz = {z, z, z, z};
            *(bh4*)&xo[(long long)(n0 + ty + 16 * r) * 512 + c0 + tx * 4] = zz;
        }
        return;
    }
    const float* xb = x + (long long)b * 512 * 3136;
    __hip_bfloat16* xnb = xn + (long long)b * 512 * 3136;
    float rs[4];
#pragma unroll
    for (int r = 0; r < 4; ++r) {
        const long long off = (long long)(c0 + ty + 16 * r) * 3136 + n0 + tx * 4;
        float4 v = *(const float4*)&xb[off];
        t[tx * 4 + 0][ty + 16 * r] = v.x;
        t[tx * 4 + 1][ty + 16 * r] = v.y;
        t[tx * 4 + 2][ty + 16 * r] = v.z;
        t[tx * 4 + 3][ty + 16 * r] = v.w;
        bh4 o = {__float2bfloat16(v.x), __float2bfloat16(v.y),
                 __float2bfloat16(v.z), __float2bfloat16(v.w)};
        *(bh4*)&xnb[off] = o;
        rs[r] = v.x + v.y + v.z + v.w;
    }
#pragma unroll
    for (int r = 0; r < 4; ++r) {
#pragma unroll
        for (int m = 1; m < 16; m <<= 1) rs[r] += __shfl_xor(rs[r], m, 16);
    }
    if (tx == 0) {
#pragma unroll
        for (int r = 0; r < 4; ++r)
            atomicAdd(&s[b * 512 + c0 + ty + 16 * r], rs[r]);
    }
    __syncthreads();
#pragma unroll
    for (int r = 0; r < 4; ++r) {
        int nn = ty + 16 * r;
        bh4 o;
        o.x = __float2bfloat16(t[nn][tx * 4 + 0]);
        o.y = __float2bfloat16(t[nn][tx * 4 + 1]);
        o.z = __float2bfloat16(t[nn][tx * 4 + 2]);
        o.w = __float2bfloat16(t[nn][tx * 4 + 3]);
        *(bh4*)&xo[(long long)(n0 + nn) * 512 + c0 + tx * 4] = o;
    }
}

// Precompute Pd=[P|P] (bf16 512x1024, P=wo·wv) and Qt (bf16 512x512, Qt=wq^T·wk).
// grid (8,8,2): z=0 -> P (NT fp32 64x64 tiles), z=1 -> Qt (TN).
__global__ __launch_bounds__(256)
void prep_pq(const float* __restrict__ wo, const float* __restrict__ wv,
             const float* __restrict__ wq, const float* __restrict__ wk,
             __hip_bfloat16* __restrict__ Pdb, __hip_bfloat16* __restrict__ Qtb)
{
    __shared__ __align__(16) float As[16][68];
    __shared__ __align__(16) float Bs[16][68];
    const int tid = threadIdx.x;
    const int tx = tid & 15, ty = tid >> 4;
    const int m0 = blockIdx.y * 64, n0 = blockIdx.x * 64;
    const bool doQ = (blockIdx.z == 1);
    const int lk = tid >> 4, lc = (tid & 15) * 4;
    const int lr = tid >> 2, lk4 = (tid & 3) * 4;
    float acc[4][4] = {};
    for (int k0 = 0; k0 < 256; k0 += 16) {
        float4 av, bv;
        if (doQ) {
            av = *(const float4*)&wq[(long long)(k0 + lk) * 512 + m0 + lc];
            bv = *(const float4*)&wk[(long long)(k0 + lk) * 512 + n0 + lc];
        } else {
            av = *(const float4*)&wo[(long long)(m0 + lr) * 256 + k0 + lk4];
            bv = *(const float4*)&wv[(long long)(k0 + lk) * 512 + n0 + lc];
        }
        __syncthreads();
        if (doQ) {
            *(float4*)&As[lk][lc] = av;
        } else {
            As[lk4 + 0][lr] = av.x; As[lk4 + 1][lr] = av.y;
            As[lk4 + 2][lr] = av.z; As[lk4 + 3][lr] = av.w;
        }
        *(float4*)&Bs[lk][lc] = bv;
        __syncthreads();
#pragma unroll
        for (int kk = 0; kk < 16; ++kk) {
            float a[4], b[4];
#pragma unroll
            for (int i = 0; i < 4; ++i) { a[i] = As[kk][ty * 4 + i]; b[i] = Bs[kk][tx * 4 + i]; }
#pragma unroll
            for (int i = 0; i < 4; ++i)
#pragma unroll
                for (int j = 0; j < 4; ++j) acc[i][j] = fmaf(a[i], b[j], acc[i][j]);
        }
    }
    const int mo = m0 + ty * 4, no = n0 + tx * 4;
    if (doQ) {
#pragma unroll
        for (int i = 0; i < 4; ++i)
#pragma unroll
            for (int j = 0; j < 4; ++j)
                Qtb[(long long)(mo + i) * 512 + no + j] = __float2bfloat16(acc[i][j]);
    } else {
#pragma unroll
        for (int i = 0; i < 4; ++i)
#pragma unroll
            for (int j = 0; j < 4; ++j) {
                __hip_bfloat16 v = __float2bfloat16(acc[i][j]);
                Pdb[(long long)(mo + i) * 1024 + no + j] = v;
                Pdb[(long long)(mo + i) * 1024 + no + j + 512] = v;
            }
    }
}

// u = wo·bv, r = bk^T·wq, w = wk^T·bq, kap = bk·bq
__global__ __launch_bounds__(256)
void prep_vec(const float* __restrict__ wo, const float* __restrict__ wq,
              const float* __restrict__ wk, const float* __restrict__ bq,
              const float* __restrict__ bk, const float* __restrict__ bv,
              float* __restrict__ u, float* __restrict__ r, float* __restrict__ w,
              float* __restrict__ kap)
{
    int c = blockIdx.x * 256 + threadIdx.x;   // 0..511
    float su = 0.f, sr = 0.f, sw = 0.f;
    for (int e = 0; e < 256; ++e) {
        su = fmaf(wo[(long long)c * 256 + e], bv[e], su);
        sr = fmaf(bk[e], wq[(long long)e * 512 + c], sr);
        sw = fmaf(wk[(long long)e * 512 + c], bq[e], sw);
    }
    u[c] = su; r[c] = sr; w[c] = sw;
    if (c == 0) {
        float k2 = 0.f;
        for (int e = 0; e < 256; ++e) k2 = fmaf(bk[e], bq[e], k2);
        *kap = k2;
    }
}

// ps = P·s, sq = Qt·s, a2 = [T·w + u(s·w) + ps·kap]/N + u·kap + bo
__global__ __launch_bounds__(256)
void vec2_kernel(const __hip_bfloat16* __restrict__ T, const __hip_bfloat16* __restrict__ Pdb,
                 const __hip_bfloat16* __restrict__ Qtb, const float* __restrict__ s,
                 const float* __restrict__ u, const float* __restrict__ w,
                 const float* __restrict__ kap, const float* __restrict__ bo,
                 float* __restrict__ ps, float* __restrict__ sq, float* __restrict__ a2)
{
    int idx = blockIdx.x * 256 + threadIdx.x;   // b*512 + c  (grid 16)
    int b = idx >> 9, c = idx & 511;
    const float* sb = s + b * 512;
    float aps = 0.f, asq = 0.f, atw = 0.f, asw = 0.f;
    for (int j = 0; j < 512; ++j) {
        float sj = sb[j];
        aps = fmaf(__bfloat162float(Pdb[(long long)c * 1024 + j]), sj, aps);
        asq = fmaf(__bfloat162float(Qtb[(long long)c * 512 + j]), sj, asq);
        atw = fmaf(__bfloat162float(T[(long long)b * 262144 + (long long)c * 512 + j]), w[j], atw);
        asw = fmaf(sj, w[j], asw);
    }
    ps[idx] = aps; sq[idx] = asq;
    float kp = *kap;
    a2[idx] = (atw + u[c] * asw + aps * kp) * (1.f / 3136.f) + u[c] * kp + bo[c];
}

// Small MFMA GEMM, 64x64 tile, 4 waves (2x2 of 32x32), both operands K-contiguous.
// MODE 4: bf16 store at column offset ks*512 (interleaved split-K partials; valid
//         because each partial of X·X^T is symmetric).
// MODE 5: plain bf16 store.
// MODE 6: bf16 store of (acc + u[m]·sq[b][n] + ps[b][m]·r[n])/N + u[m]·r[n].
template<int MODE, int BKT>
__global__ __launch_bounds__(256)
void mfma_sm(const __hip_bfloat16* __restrict__ A, long long sA, int lda,
             const __hip_bfloat16* __restrict__ B, long long sB, int ldb,
             __hip_bfloat16* __restrict__ C, long long sC, int ldc,
             const float* __restrict__ pu, const float* __restrict__ pr,
             const float* __restrict__ pps, const float* __restrict__ psq,
             int kLen, int nSplit)
{
    constexpr int CPR = BKT / 8;
    constexpr int NC = 64 * CPR / 256;   // chunks/thread per matrix (1 or 2)
    __shared__ __hip_bfloat16 As[64 * BKT];
    __shared__ __hip_bfloat16 Bs[64 * BKT];
    const int tid = threadIdx.x;
    const int lane = tid & 63;
    const int w = tid >> 6;
    const int wm = (w >> 1) << 5;
    const int wn = (w & 1) << 5;
    const int ln = lane & 15;
    const int hi = lane >> 4;
    const int bz = blockIdx.z;
    const int batch = bz / nSplit;
    const int ks = bz - batch * nSplit;
    const int m0 = blockIdx.y << 6;
    const int n0 = blockIdx.x << 6;
    const long long k0 = (long long)ks * kLen;

#define SWZ(row) ((BKT == 64) ? ((row) & 7) : (((row) >> 1) & 3))
    const __hip_bfloat16* gA[NC];
    const __hip_bfloat16* gB[NC];
#pragma unroll
    for (int p = 0; p < NC; ++p) {
        int q = tid + 256 * p;
        int row = q / CPR;
        int c = (q % CPR) ^ SWZ(row);
        gA[p] = A + batch * sA + (long long)(m0 + row) * lda + k0 + c * 8;
        gB[p] = B + batch * sB + (long long)(n0 + row) * ldb + k0 + c * 8;
    }
    floatx4 acc[2][2] = {};
    const int nK = kLen / BKT;
    for (int kt = 0; kt < nK; ++kt) {
#pragma unroll
        for (int p = 0; p < NC; ++p) {
            load_lds16(gA[p], As + (tid + 256 * p) * 8);
            load_lds16(gB[p], Bs + (tid + 256 * p) * 8);
            gA[p] += BKT; gB[p] += BKT;
        }
        __syncthreads();
#pragma unroll
        for (int kk = 0; kk < BKT / 32; ++kk) {
            const int cidx = kk * 4 + hi;
            bf16x8 af[2], bfr[2];
#pragma unroll
            for (int i = 0; i < 2; ++i) {
                int row = wm + i * 16 + ln;
                af[i] = *(const bf16x8*)(As + row * BKT + ((cidx ^ SWZ(row)) << 3));
            }
#pragma unroll
            for (int j = 0; j < 2; ++j) {
                int row = wn + j * 16 + ln;
                bfr[j] = *(const bf16x8*)(Bs + row * BKT + ((cidx ^ SWZ(row)) << 3));
            }
#pragma unroll
            for (int i = 0; i < 2; ++i)
#pragma unroll
                for (int j = 0; j < 2; ++j)
                    acc[i][j] = __builtin_amdgcn_mfma_f32_16x16x32_bf16(af[i], bfr[j], acc[i][j], 0, 0, 0);
        }
        __syncthreads();
    }
#undef SWZ

    // C/D layout: col = lane&15, row = (lane>>4)*4 + r  [m89-verified]
    __hip_bfloat16* Cb = C + batch * sC;
#pragma unroll
    for (int i = 0; i < 2; ++i) {
        int mb = m0 + wm + i * 16 + hi * 4;
#pragma unroll
        for (int r = 0; r < 4; ++r) {
#pragma unroll
            for (int j = 0; j < 2; ++j) {
                int nl = n0 + wn + j * 16 + ln;
                float v = acc[i][j][r];
                if (MODE == 6) {
                    float uu = pu[mb + r], rr = pr[nl];
                    v = (v + uu * psq[batch * 512 + nl] + pps[batch * 512 + mb + r] * rr)
                        * (1.f / 3136.f) + uu * rr;
                    Cb[(long long)(mb + r) * ldc + nl] = __float2bfloat16(v);
                } else if (MODE == 4) {
                    Cb[(long long)(mb + r) * ldc + ks * 512 + nl] = __float2bfloat16(v);
                } else {
                    Cb[(long long)(mb + r) * ldc + nl] = __float2bfloat16(v);
                }
            }
        }
    }
}

// Final MFMA GEMM (round-4 proven): 64(M)x128(N) tile, 4 waves (64x32 each), BK=64.
// MODE 2: fp32 out = acc + bias[b][m] + xres[b][m][n], store only n<Nreal.
template<int MODE, int BKT>
__global__ __launch_bounds__(256)
void mfma64(const __hip_bfloat16* __restrict__ A, long long sA, int lda,
            const __hip_bfloat16* __restrict__ B, long long sB, int ldb,
            float* __restrict__ C, long long sC, int ldc,
            const float* __restrict__ bias, int sBias,
            const float* __restrict__ xres, long long sX,
            int kLen, int nSplit, int Nreal)
{
    constexpr int CPR = BKT / 8;
    constexpr int NA = 64 * CPR / 256;
    constexpr int NB = 128 * CPR / 256;
    __shared__ __hip_bfloat16 As[64 * BKT];
    __shared__ __hip_bfloat16 Bs[128 * BKT];
    const int tid = threadIdx.x;
    const int lane = tid & 63;
    const int w = tid >> 6;
    const int ln = lane & 15;
    const int hi = lane >> 4;
    const int bz = blockIdx.z;
    const int batch = bz / nSplit;
    const int m0 = blockIdx.y << 6;
    const int n0 = blockIdx.x << 7;
    const long long k0 = 0;

#define SWZ(row) ((BKT == 64) ? ((row) & 7) : (((row) >> 1) & 3))
    const __hip_bfloat16* gA[NA];
    const __hip_bfloat16* gB[NB];
#pragma unroll
    for (int p = 0; p < NA; ++p) {
        int q = tid + 256 * p;
        int row = q / CPR;
        int c = (q % CPR) ^ SWZ(row);
        gA[p] = A + batch * sA + (long long)(m0 + row) * lda + k0 + c * 8;
    }
#pragma unroll
    for (int p = 0; p < NB; ++p) {
        int q = tid + 256 * p;
        int row = q / CPR;
        int c = (q % CPR) ^ SWZ(row);
        gB[p] = B + batch * sB + (long long)(n0 + row) * ldb + k0 + c * 8;
    }

    floatx4 acc[4][2] = {};
    const int nK = kLen / BKT;
    for (int kt = 0; kt < nK; ++kt) {
#pragma unroll
        for (int p = 0; p < NA; ++p) {
            load_lds16(gA[p], As + (tid + 256 * p) * 8);
            gA[p] += BKT;
        }
#pragma unroll
        for (int p = 0; p < NB; ++p) {
            load_lds16(gB[p], Bs + (tid + 256 * p) * 8);
            gB[p] += BKT;
        }
        __syncthreads();
#pragma unroll
        for (int kk = 0; kk < BKT / 32; ++kk) {
            const int cidx = kk * 4 + hi;
            bf16x8 af[4], bfr[2];
#pragma unroll
            for (int i = 0; i < 4; ++i) {
                int row = i * 16 + ln;
                af[i] = *(const bf16x8*)(As + row * BKT + ((cidx ^ SWZ(row)) << 3));
            }
#pragma unroll
            for (int j = 0; j < 2; ++j) {
                int row = w * 32 + j * 16 + ln;
                bfr[j] = *(const bf16x8*)(Bs + row * BKT + ((cidx ^ SWZ(row)) << 3));
            }
#pragma unroll
            for (int i = 0; i < 4; ++i)
#pragma unroll
                for (int j = 0; j < 2; ++j)
                    acc[i][j] = __builtin_amdgcn_mfma_f32_16x16x32_bf16(af[i], bfr[j], acc[i][j], 0, 0, 0);
        }
        __syncthreads();
    }
#undef SWZ

    float* Cb = C + batch * sC;
    const float* xb = xres + batch * sX;
#pragma unroll
    for (int i = 0; i < 4; ++i) {
        int mb = m0 + i * 16 + hi * 4;
#pragma unroll
        for (int r = 0; r < 4; ++r) {
            float bb = bias[batch * sBias + mb + r];
#pragma unroll
            for (int j = 0; j < 2; ++j) {
                int nl = n0 + w * 32 + j * 16 + ln;
                if (nl < Nreal) {
                    long long off = (long long)(mb + r) * ldc + nl;
                    Cb[off] = acc[i][j][r] + bb + xb[off];
                }
            }
        }
    }
}

extern "C" void kernel_launch(void* const* d_in, const int* in_sizes, int n_in,
                              void* d_out, int out_size, void* d_ws, size_t ws_size,
                              hipStream_t stream)
{
    const float* x  = (const float*)d_in[0];
    const float* wq = (const float*)d_in[1];
    const float* bq = (const float*)d_in[2];
    const float* wk = (const float*)d_in[3];
    const float* bk = (const float*)d_in[4];
    const float* wv = (const float*)d_in[5];
    const float* bv = (const float*)d_in[6];
    const float* wo = (const float*)d_in[7];
    const float* bo = (const float*)d_in[8];
    float* out = (float*)d_out;

    const int C = 512, N = 3136;
    const long long xs = (long long)C * N;   // 1,605,632

    // d_out scratch (51,380,224 B), all dead before the final GEMM writes out:
    char* ob = (char*)d_out;
    __hip_bfloat16* xn  = (__hip_bfloat16*)ob;                 // @0: 25,690,112 (dead after G)
    __hip_bfloat16* Gp2 = (__hip_bfloat16*)(ob + 25690112);    // 8x512x1024 bf16 = 8,388,608
    __hip_bfloat16* Tb  = (__hip_bfloat16*)(ob + 34078720);    // 8x512x512 bf16 = 4,194,304

    // ws (~32.05 MB, within proven 33 MB budget). Final GEMM reads only from here + x.
    char* wsb = (char*)d_ws;
    __hip_bfloat16* xT  = (__hip_bfloat16*)wsb;                // 26,214,400
    __hip_bfloat16* A2b = (__hip_bfloat16*)(wsb + 26214400);   //  4,194,304
    __hip_bfloat16* Pdb = (__hip_bfloat16*)(wsb + 30408704);   //  1,048,576
    __hip_bfloat16* Qtb = (__hip_bfloat16*)(wsb + 31457280);   //    524,288
    float* sv  = (float*)(wsb + 31981568);                     //     16,384
    float* u_  = (float*)(wsb + 31997952);                     //      2,048
    float* r_  = (float*)(wsb + 32000000);                     //      2,048
    float* w_  = (float*)(wsb + 32002048);                     //      2,048
    float* kap = (float*)(wsb + 32004096);                     //         16
    float* ps  = (float*)(wsb + 32004112);                     //     16,384
    float* sq  = (float*)(wsb + 32020496);                     //     16,384
    float* a2v = (float*)(wsb + 32036880);                     //     16,384

    // 1) data-independent precompute
    prep_pq<<<dim3(8, 8, 2), 256, 0, stream>>>(wo, wv, wq, wk, Pdb, Qtb);
    prep_vec<<<2, 256, 0, stream>>>(wo, wq, wk, bq, bk, bv, u_, r_, w_, kap);

    // 2) zero s, then xT + xn + s
    zero_f4<<<1, 256, 0, stream>>>((float4*)sv, 1024);
    transpose_conv<<<dim3(50, 8, 8), 256, 0, stream>>>(x, xT, xn, sv);

    // 3) Gp2[b][c][ks*512+c'] = bf16 partial of X·X^T  (split-K=2, K=1568 each)
    //    1024 blocks = 4/CU, atomic-free (symmetric partials -> direct store)
    mfma_sm<4, 32><<<dim3(8, 8, 16), 256, 0, stream>>>(
        xn, xs, N, xn, xs, N, Gp2, 524288, 1024,
        nullptr, nullptr, nullptr, nullptr, 1568, 2);

    // 4) T = Pd·Gp2  (K=1024 folds the split-K reduce), bf16 out
    mfma_sm<5, 64><<<dim3(8, 8, 8), 256, 0, stream>>>(
        Pdb, 0, 1024, Gp2, 524288, 1024, Tb, 262144, 512,
        nullptr, nullptr, nullptr, nullptr, 1024, 1);

    // 5) ps = P·s, sq = Qt·s, a2 = [T·w + u(s·w) + ps·κ]/N + uκ + bo
    vec2_kernel<<<16, 256, 0, stream>>>(Tb, Pdb, Qtb, sv, u_, w_, kap, bo, ps, sq, a2v);

    // 6) A2 = [T·Q + u·sq^T + ps·r^T]/N + u·r^T  -> bf16
    mfma_sm<6, 64><<<dim3(8, 8, 8), 256, 0, stream>>>(
        Tb, 262144, 512, Qtb, 0, 512, A2b, 262144, 512,
        u_, r_, ps, sq, 512, 1);

    // 7) out = A2·X + a2 + x   (M=512, N=3136, K=512), 1600 blocks
    mfma64<2, 64><<<dim3(25, 8, 8), 256, 0, stream>>>(
        A2b, 262144, 512, xT, 3200LL * 512, 512,
        out, xs, N, a2v, 512, x, xs, 512, 1, N);
}

// Round 6
// 255.832 us; speedup vs baseline: 1.5021x; 1.2135x over previous
//
#include <hip/hip_runtime.h>
#include <hip/hip_bf16.h>

// DotProductNonLocalBlock: B=8, C=512, N=3136 (pad 3200), E=256.
// No softmax => fully associative. Factored with DATA-INDEPENDENT
// P = wo·wv, Qt = wq^T·wk, u = wo·bv, r = bk^T·wq, w = Wk^T·bq, κ = bk·bq:
//   G  = X·X^T          [bf16 MFMA, split-K=2, bf16 partials col-interleaved]
//   T  = Pd·Gp2 (K=1024 folds the reduce)
//   A2 = [T·Q + u·(Qt s)^T + (P s)·r^T]/N + u·r^T
//   a2 = [T·w + u·(s·w) + (P s)·κ]/N + u·κ + bo
//   Out = A2·X + a2 + X
// All MFMA grids put batch in blockIdx.x (XCD affinity: per-batch slices fit 4MB L2).

typedef __attribute__((ext_vector_type(8))) __bf16 bf16x8;
typedef __attribute__((ext_vector_type(4))) float floatx4;

struct __align__(8) bh4 { __hip_bfloat16 x, y, z, w; };

__device__ __forceinline__ void load_lds16(const void* g, void* l) {
    __builtin_amdgcn_global_load_lds((const __attribute__((address_space(1))) void*)g,
                                     (__attribute__((address_space(3))) void*)l, 16, 0, 0);
}

__global__ void zero_f4(float4* __restrict__ p, int n4) {
    int i = blockIdx.x * 256 + threadIdx.x;
    if (i < n4) p[i] = make_float4(0.f, 0.f, 0.f, 0.f);
}

// x [b][512][3136] fp32 -> xT [b][3200][512] bf16 (pad rows zero)
//                        + xnp [b][512][3200] bf16 (pad cols zero)
//                        + s[b][c] += rowsums (atomic)
__global__ __launch_bounds__(256)
void transpose_conv(const float* __restrict__ x, __hip_bfloat16* __restrict__ xT,
                    __hip_bfloat16* __restrict__ xnp, float* __restrict__ s)
{
    __shared__ float t[64][65];
    const int b = blockIdx.z;
    const int n0 = blockIdx.x * 64, c0 = blockIdx.y * 64;
    const int tx = threadIdx.x & 15, ty = threadIdx.x >> 4;
    __hip_bfloat16* xo = xT + (long long)b * 3200 * 512;
    __hip_bfloat16* xnb = xnp + (long long)b * 512 * 3200;
    const __hip_bfloat16 z = __float2bfloat16(0.f);
    if (n0 >= 3136) {   // pad tile: zero xT rows and xnp cols
        bh4 zz = {z, z, z, z};
#pragma unroll
        for (int r = 0; r < 4; ++r) {
            *(bh4*)&xo[(long long)(n0 + ty + 16 * r) * 512 + c0 + tx * 4] = zz;
            *(bh4*)&xnb[(long long)(c0 + ty + 16 * r) * 3200 + n0 + tx * 4] = zz;
        }
        return;
    }
    const float* xb = x + (long long)b * 512 * 3136;
    float rs[4];
#pragma unroll
    for (int r = 0; r < 4; ++r) {
        float4 v = *(const float4*)&xb[(long long)(c0 + ty + 16 * r) * 3136 + n0 + tx * 4];
        t[tx * 4 + 0][ty + 16 * r] = v.x;
        t[tx * 4 + 1][ty + 16 * r] = v.y;
        t[tx * 4 + 2][ty + 16 * r] = v.z;
        t[tx * 4 + 3][ty + 16 * r] = v.w;
        bh4 o = {__float2bfloat16(v.x), __float2bfloat16(v.y),
                 __float2bfloat16(v.z), __float2bfloat16(v.w)};
        *(bh4*)&xnb[(long long)(c0 + ty + 16 * r) * 3200 + n0 + tx * 4] = o;
        rs[r] = v.x + v.y + v.z + v.w;
    }
#pragma unroll
    for (int r = 0; r < 4; ++r) {
#pragma unroll
        for (int m = 1; m < 16; m <<= 1) rs[r] += __shfl_xor(rs[r], m, 16);
    }
    if (tx == 0) {
#pragma unroll
        for (int r = 0; r < 4; ++r)
            atomicAdd(&s[b * 512 + c0 + ty + 16 * r], rs[r]);
    }
    __syncthreads();
#pragma unroll
    for (int r = 0; r < 4; ++r) {
        int nn = ty + 16 * r;
        bh4 o;
        o.x = __float2bfloat16(t[nn][tx * 4 + 0]);
        o.y = __float2bfloat16(t[nn][tx * 4 + 1]);
        o.z = __float2bfloat16(t[nn][tx * 4 + 2]);
        o.w = __float2bfloat16(t[nn][tx * 4 + 3]);
        *(bh4*)&xo[(long long)(n0 + nn) * 512 + c0 + tx * 4] = o;
    }
}

// Precompute Pd=[P|P] (bf16 512x1024, P=wo·wv) and Qt (bf16 512x512, Qt=wq^T·wk).
__global__ __launch_bounds__(256)
void prep_pq(const float* __restrict__ wo, const float* __restrict__ wv,
             const float* __restrict__ wq, const float* __restrict__ wk,
             __hip_bfloat16* __restrict__ Pdb, __hip_bfloat16* __restrict__ Qtb)
{
    __shared__ __align__(16) float As[16][68];
    __shared__ __align__(16) float Bs[16][68];
    const int tid = threadIdx.x;
    const int tx = tid & 15, ty = tid >> 4;
    const int m0 = blockIdx.y * 64, n0 = blockIdx.x * 64;
    const bool doQ = (blockIdx.z == 1);
    const int lk = tid >> 4, lc = (tid & 15) * 4;
    const int lr = tid >> 2, lk4 = (tid & 3) * 4;
    float acc[4][4] = {};
    for (int k0 = 0; k0 < 256; k0 += 16) {
        float4 av, bv;
        if (doQ) {
            av = *(const float4*)&wq[(long long)(k0 + lk) * 512 + m0 + lc];
            bv = *(const float4*)&wk[(long long)(k0 + lk) * 512 + n0 + lc];
        } else {
            av = *(const float4*)&wo[(long long)(m0 + lr) * 256 + k0 + lk4];
            bv = *(const float4*)&wv[(long long)(k0 + lk) * 512 + n0 + lc];
        }
        __syncthreads();
        if (doQ) {
            *(float4*)&As[lk][lc] = av;
        } else {
            As[lk4 + 0][lr] = av.x; As[lk4 + 1][lr] = av.y;
            As[lk4 + 2][lr] = av.z; As[lk4 + 3][lr] = av.w;
        }
        *(float4*)&Bs[lk][lc] = bv;
        __syncthreads();
#pragma unroll
        for (int kk = 0; kk < 16; ++kk) {
            float a[4], b[4];
#pragma unroll
            for (int i = 0; i < 4; ++i) { a[i] = As[kk][ty * 4 + i]; b[i] = Bs[kk][tx * 4 + i]; }
#pragma unroll
            for (int i = 0; i < 4; ++i)
#pragma unroll
                for (int j = 0; j < 4; ++j) acc[i][j] = fmaf(a[i], b[j], acc[i][j]);
        }
    }
    const int mo = m0 + ty * 4, no = n0 + tx * 4;
    if (doQ) {
#pragma unroll
        for (int i = 0; i < 4; ++i)
#pragma unroll
            for (int j = 0; j < 4; ++j)
                Qtb[(long long)(mo + i) * 512 + no + j] = __float2bfloat16(acc[i][j]);
    } else {
#pragma unroll
        for (int i = 0; i < 4; ++i)
#pragma unroll
            for (int j = 0; j < 4; ++j) {
                __hip_bfloat16 v = __float2bfloat16(acc[i][j]);
                Pdb[(long long)(mo + i) * 1024 + no + j] = v;
                Pdb[(long long)(mo + i) * 1024 + no + j + 512] = v;
            }
    }
}

// u = wo·bv, r = bk^T·wq, w = wk^T·bq, kap = bk·bq
__global__ __launch_bounds__(256)
void prep_vec(const float* __restrict__ wo, const float* __restrict__ wq,
              const float* __restrict__ wk, const float* __restrict__ bq,
              const float* __restrict__ bk, const float* __restrict__ bv,
              float* __restrict__ u, float* __restrict__ r, float* __restrict__ w,
              float* __restrict__ kap)
{
    int c = blockIdx.x * 256 + threadIdx.x;   // 0..511
    float su = 0.f, sr = 0.f, sw = 0.f;
    for (int e = 0; e < 256; ++e) {
        su = fmaf(wo[(long long)c * 256 + e], bv[e], su);
        sr = fmaf(bk[e], wq[(long long)e * 512 + c], sr);
        sw = fmaf(wk[(long long)e * 512 + c], bq[e], sw);
    }
    u[c] = su; r[c] = sr; w[c] = sw;
    if (c == 0) {
        float k2 = 0.f;
        for (int e = 0; e < 256; ++e) k2 = fmaf(bk[e], bq[e], k2);
        *kap = k2;
    }
}

// Wave-per-output: ps = P·s, sq = Qt·s, a2 = [T·w + u(s·w) + ps·κ]/N + uκ + bo.
// grid 1024 blocks x 256 thr; wave handles one (b,c).
__global__ __launch_bounds__(256)
void vec2_kernel(const __hip_bfloat16* __restrict__ T, const __hip_bfloat16* __restrict__ Pdb,
                 const __hip_bfloat16* __restrict__ Qtb, const float* __restrict__ s,
                 const float* __restrict__ u, const float* __restrict__ w,
                 const float* __restrict__ kap, const float* __restrict__ bo,
                 float* __restrict__ ps, float* __restrict__ sq, float* __restrict__ a2)
{
    const int idx = blockIdx.x * 4 + (threadIdx.x >> 6);   // 0..4095 = b*512+c
    const int lane = threadIdx.x & 63;
    const int b = idx >> 9, c = idx & 511;
    const int j0 = lane * 8;
    const float* sb = s + b * 512;
    float4 s0 = *(const float4*)&sb[j0], s1 = *(const float4*)&sb[j0 + 4];
    float4 w0 = *(const float4*)&w[j0],  w1 = *(const float4*)&w[j0 + 4];
    bf16x8 pv = *(const bf16x8*)&Pdb[(long long)c * 1024 + j0];
    bf16x8 qv = *(const bf16x8*)&Qtb[(long long)c * 512 + j0];
    bf16x8 tv = *(const bf16x8*)&T[(long long)b * 262144 + (long long)c * 512 + j0];
    float sj[8] = {s0.x, s0.y, s0.z, s0.w, s1.x, s1.y, s1.z, s1.w};
    float wj[8] = {w0.x, w0.y, w0.z, w0.w, w1.x, w1.y, w1.z, w1.w};
    float aps = 0.f, asq = 0.f, atw = 0.f, asw = 0.f;
#pragma unroll
    for (int t = 0; t < 8; ++t) {
        aps = fmaf((float)pv[t], sj[t], aps);
        asq = fmaf((float)qv[t], sj[t], asq);
        atw = fmaf((float)tv[t], wj[t], atw);
        asw = fmaf(sj[t], wj[t], asw);
    }
#pragma unroll
    for (int m = 1; m < 64; m <<= 1) {
        aps += __shfl_xor(aps, m);
        asq += __shfl_xor(asq, m);
        atw += __shfl_xor(atw, m);
        asw += __shfl_xor(asw, m);
    }
    if (lane == 0) {
        ps[idx] = aps; sq[idx] = asq;
        float kp = *kap;
        a2[idx] = (atw + u[c] * asw + aps * kp) * (1.f / 3136.f) + u[c] * kp + bo[c];
    }
}

// Small MFMA GEMM, 64x64 tile, 4 waves (2x2 of 32x32), operands K-contiguous.
// Grid: blockIdx.x = batch + 8*ks (XCD affinity), y = n-tile, z = m-tile.
// MODE 4: bf16 store at column offset ks*512 (interleaved split-K partials;
//         valid because each partial of X·X^T is symmetric).
// MODE 5: plain bf16 store.
// MODE 6: bf16 store of (acc + u[m]·sq[b][n] + ps[b][m]·r[n])/N + u[m]·r[n].
template<int MODE, int BKT>
__global__ __launch_bounds__(256)
void mfma_sm(const __hip_bfloat16* __restrict__ A, long long sA, int lda,
             const __hip_bfloat16* __restrict__ B, long long sB, int ldb,
             __hip_bfloat16* __restrict__ C, long long sC, int ldc,
             const float* __restrict__ pu, const float* __restrict__ pr,
             const float* __restrict__ pps, const float* __restrict__ psq,
             int kLen)
{
    constexpr int CPR = BKT / 8;
    constexpr int NC = 64 * CPR / 256;   // chunks/thread per matrix
    __shared__ __hip_bfloat16 As[64 * BKT];
    __shared__ __hip_bfloat16 Bs[64 * BKT];
    const int tid = threadIdx.x;
    const int lane = tid & 63;
    const int w = tid >> 6;
    const int wm = (w >> 1) << 5;
    const int wn = (w & 1) << 5;
    const int ln = lane & 15;
    const int hi = lane >> 4;
    const int bx = blockIdx.x;
    const int batch = bx & 7, ks = bx >> 3;
    const int m0 = blockIdx.z << 6;
    const int n0 = blockIdx.y << 6;
    const long long k0 = (long long)ks * kLen;

#define SWZ(row) ((BKT == 64) ? ((row) & 7) : (((row) >> 1) & 3))
    const __hip_bfloat16* gA[NC];
    const __hip_bfloat16* gB[NC];
#pragma unroll
    for (int p = 0; p < NC; ++p) {
        int q = tid + 256 * p;
        int row = q / CPR;
        int c = (q % CPR) ^ SWZ(row);
        gA[p] = A + batch * sA + (long long)(m0 + row) * lda + k0 + c * 8;
        gB[p] = B + batch * sB + (long long)(n0 + row) * ldb + k0 + c * 8;
    }
    floatx4 acc[2][2] = {};
    const int nK = kLen / BKT;
    for (int kt = 0; kt < nK; ++kt) {
#pragma unroll
        for (int p = 0; p < NC; ++p) {
            load_lds16(gA[p], As + (tid + 256 * p) * 8);
            load_lds16(gB[p], Bs + (tid + 256 * p) * 8);
            gA[p] += BKT; gB[p] += BKT;
        }
        __syncthreads();
#pragma unroll
        for (int kk = 0; kk < BKT / 32; ++kk) {
            const int cidx = kk * 4 + hi;
            bf16x8 af[2], bfr[2];
#pragma unroll
            for (int i = 0; i < 2; ++i) {
                int row = wm + i * 16 + ln;
                af[i] = *(const bf16x8*)(As + row * BKT + ((cidx ^ SWZ(row)) << 3));
            }
#pragma unroll
            for (int j = 0; j < 2; ++j) {
                int row = wn + j * 16 + ln;
                bfr[j] = *(const bf16x8*)(Bs + row * BKT + ((cidx ^ SWZ(row)) << 3));
            }
#pragma unroll
            for (int i = 0; i < 2; ++i)
#pragma unroll
                for (int j = 0; j < 2; ++j)
                    acc[i][j] = __builtin_amdgcn_mfma_f32_16x16x32_bf16(af[i], bfr[j], acc[i][j], 0, 0, 0);
        }
        __syncthreads();
    }
#undef SWZ

    // C/D layout: col = lane&15, row = (lane>>4)*4 + r  [m89-verified]
    __hip_bfloat16* Cb = C + batch * sC;
#pragma unroll
    for (int i = 0; i < 2; ++i) {
        int mb = m0 + wm + i * 16 + hi * 4;
#pragma unroll
        for (int r = 0; r < 4; ++r) {
#pragma unroll
            for (int j = 0; j < 2; ++j) {
                int nl = n0 + wn + j * 16 + ln;
                float v = acc[i][j][r];
                if (MODE == 6) {
                    float uu = pu[mb + r], rr = pr[nl];
                    v = (v + uu * psq[batch * 512 + nl] + pps[batch * 512 + mb + r] * rr)
                        * (1.f / 3136.f) + uu * rr;
                    Cb[(long long)(mb + r) * ldc + nl] = __float2bfloat16(v);
                } else if (MODE == 4) {
                    Cb[(long long)(mb + r) * ldc + ks * 512 + nl] = __float2bfloat16(v);
                } else {
                    Cb[(long long)(mb + r) * ldc + nl] = __float2bfloat16(v);
                }
            }
        }
    }
}

// Final MFMA GEMM: 64(M)x128(N) tile, 4 waves (64x32 each), BK=64.
// Grid: blockIdx.x = batch (XCD affinity), y = n-tile (25), z = m-tile (8).
// out = acc + bias[b][m] + xres[b][m][n], store only n<Nreal.
template<int BKT>
__global__ __launch_bounds__(256)
void mfma64(const __hip_bfloat16* __restrict__ A, long long sA, int lda,
            const __hip_bfloat16* __restrict__ B, long long sB, int ldb,
            float* __restrict__ C, long long sC, int ldc,
            const float* __restrict__ bias, int sBias,
            const float* __restrict__ xres, long long sX,
            int kLen, int Nreal)
{
    constexpr int CPR = BKT / 8;
    constexpr int NA = 64 * CPR / 256;
    constexpr int NB = 128 * CPR / 256;
    __shared__ __hip_bfloat16 As[64 * BKT];
    __shared__ __hip_bfloat16 Bs[128 * BKT];
    const int tid = threadIdx.x;
    const int lane = tid & 63;
    const int w = tid >> 6;
    const int ln = lane & 15;
    const int hi = lane >> 4;
    const int batch = blockIdx.x;
    const int m0 = blockIdx.z << 6;
    const int n0 = blockIdx.y << 7;

#define SWZ(row) ((BKT == 64) ? ((row) & 7) : (((row) >> 1) & 3))
    const __hip_bfloat16* gA[NA];
    const __hip_bfloat16* gB[NB];
#pragma unroll
    for (int p = 0; p < NA; ++p) {
        int q = tid + 256 * p;
        int row = q / CPR;
        int c = (q % CPR) ^ SWZ(row);
        gA[p] = A + batch * sA + (long long)(m0 + row) * lda + c * 8;
    }
#pragma unroll
    for (int p = 0; p < NB; ++p) {
        int q = tid + 256 * p;
        int row = q / CPR;
        int c = (q % CPR) ^ SWZ(row);
        gB[p] = B + batch * sB + (long long)(n0 + row) * ldb + c * 8;
    }

    floatx4 acc[4][2] = {};
    const int nK = kLen / BKT;
    for (int kt = 0; kt < nK; ++kt) {
#pragma unroll
        for (int p = 0; p < NA; ++p) {
            load_lds16(gA[p], As + (tid + 256 * p) * 8);
            gA[p] += BKT;
        }
#pragma unroll
        for (int p = 0; p < NB; ++p) {
            load_lds16(gB[p], Bs + (tid + 256 * p) * 8);
            gB[p] += BKT;
        }
        __syncthreads();
#pragma unroll
        for (int kk = 0; kk < BKT / 32; ++kk) {
            const int cidx = kk * 4 + hi;
            bf16x8 af[4], bfr[2];
#pragma unroll
            for (int i = 0; i < 4; ++i) {
                int row = i * 16 + ln;
                af[i] = *(const bf16x8*)(As + row * BKT + ((cidx ^ SWZ(row)) << 3));
            }
#pragma unroll
            for (int j = 0; j < 2; ++j) {
                int row = w * 32 + j * 16 + ln;
                bfr[j] = *(const bf16x8*)(Bs + row * BKT + ((cidx ^ SWZ(row)) << 3));
            }
#pragma unroll
            for (int i = 0; i < 4; ++i)
#pragma unroll
                for (int j = 0; j < 2; ++j)
                    acc[i][j] = __builtin_amdgcn_mfma_f32_16x16x32_bf16(af[i], bfr[j], acc[i][j], 0, 0, 0);
        }
        __syncthreads();
    }
#undef SWZ

    float* Cb = C + batch * sC;
    const float* xb = xres + batch * sX;
#pragma unroll
    for (int i = 0; i < 4; ++i) {
        int mb = m0 + i * 16 + hi * 4;
#pragma unroll
        for (int r = 0; r < 4; ++r) {
            float bb = bias[batch * sBias + mb + r];
#pragma unroll
            for (int j = 0; j < 2; ++j) {
                int nl = n0 + w * 32 + j * 16 + ln;
                if (nl < Nreal) {
                    long long off = (long long)(mb + r) * ldc + nl;
                    Cb[off] = acc[i][j][r] + bb + xb[off];
                }
            }
        }
    }
}

extern "C" void kernel_launch(void* const* d_in, const int* in_sizes, int n_in,
                              void* d_out, int out_size, void* d_ws, size_t ws_size,
                              hipStream_t stream)
{
    const float* x  = (const float*)d_in[0];
    const float* wq = (const float*)d_in[1];
    const float* bq = (const float*)d_in[2];
    const float* wk = (const float*)d_in[3];
    const float* bk = (const float*)d_in[4];
    const float* wv = (const float*)d_in[5];
    const float* bv = (const float*)d_in[6];
    const float* wo = (const float*)d_in[7];
    const float* bo = (const float*)d_in[8];
    float* out = (float*)d_out;

    const int C = 512, N = 3136;
    const long long xs = (long long)C * N;        // 1,605,632
    const long long xs2 = 512LL * 3200;           // xnp per-batch stride

    // d_out scratch (51.4 MB), all dead before the final GEMM writes out:
    char* ob = (char*)d_out;
    __hip_bfloat16* xnp = (__hip_bfloat16*)ob;                 // @0: 26,214,400 (dead after G)
    __hip_bfloat16* Gp2 = (__hip_bfloat16*)(ob + 26214400);    // 8x512x1024 bf16 = 8,388,608
    __hip_bfloat16* Tb  = (__hip_bfloat16*)(ob + 34603008);    // 8x512x512 bf16 = 4,194,304

    // ws (~32.05 MB, proven budget). Final GEMM reads only ws + x.
    char* wsb = (char*)d_ws;
    __hip_bfloat16* xT  = (__hip_bfloat16*)wsb;                // 26,214,400
    __hip_bfloat16* A2b = (__hip_bfloat16*)(wsb + 26214400);   //  4,194,304
    __hip_bfloat16* Pdb = (__hip_bfloat16*)(wsb + 30408704);   //  1,048,576
    __hip_bfloat16* Qtb = (__hip_bfloat16*)(wsb + 31457280);   //    524,288
    float* sv  = (float*)(wsb + 31981568);                     //     16,384
    float* u_  = (float*)(wsb + 31997952);                     //      2,048
    float* r_  = (float*)(wsb + 32000000);                     //      2,048
    float* w_  = (float*)(wsb + 32002048);                     //      2,048
    float* kap = (float*)(wsb + 32004096);                     //         16
    float* ps  = (float*)(wsb + 32004112);                     //     16,384
    float* sq  = (float*)(wsb + 32020496);                     //     16,384
    float* a2v = (float*)(wsb + 32036880);                     //     16,384

    // 1) data-independent precompute
    prep_pq<<<dim3(8, 8, 2), 256, 0, stream>>>(wo, wv, wq, wk, Pdb, Qtb);
    prep_vec<<<2, 256, 0, stream>>>(wo, wq, wk, bq, bk, bv, u_, r_, w_, kap);

    // 2) zero s (4096 floats = 1024 float4), then xT + xnp + s
    zero_f4<<<4, 256, 0, stream>>>((float4*)sv, 1024);
    transpose_conv<<<dim3(50, 8, 8), 256, 0, stream>>>(x, xT, xnp, sv);

    // 3) Gp2[b][c][ks*512+c'] = bf16 partial of X·X^T  (split-K=2, K=1600, BK=64)
    //    grid x = batch + 8*ks -> per-XCD working set = one batch slice
    mfma_sm<4, 64><<<dim3(16, 8, 8), 256, 0, stream>>>(
        xnp, xs2, 3200, xnp, xs2, 3200, Gp2, 524288, 1024,
        nullptr, nullptr, nullptr, nullptr, 1600);

    // 4) T = Pd·Gp2  (K=1024 folds the split-K reduce)
    mfma_sm<5, 64><<<dim3(8, 8, 8), 256, 0, stream>>>(
        Pdb, 0, 1024, Gp2, 524288, 1024, Tb, 262144, 512,
        nullptr, nullptr, nullptr, nullptr, 1024);

    // 5) ps = P·s, sq = Qt·s, a2 = [T·w + u(s·w) + ps·κ]/N + uκ + bo
    vec2_kernel<<<1024, 256, 0, stream>>>(Tb, Pdb, Qtb, sv, u_, w_, kap, bo, ps, sq, a2v);

    // 6) A2 = [T·Q + u·sq^T + ps·r^T]/N + u·r^T  -> bf16
    mfma_sm<6, 64><<<dim3(8, 8, 8), 256, 0, stream>>>(
        Tb, 262144, 512, Qtb, 0, 512, A2b, 262144, 512,
        u_, r_, ps, sq, 512);

    // 7) out = A2·X + a2 + x   (M=512, N=3136, K=512)
    mfma64<64><<<dim3(8, 25, 8), 256, 0, stream>>>(
        A2b, 262144, 512, xT, 3200LL * 512, 512,
        out, xs, N, a2v, 512, x, xs, 512, N);
}

// Round 7
// 227.478 us; speedup vs baseline: 1.6893x; 1.1246x over previous
//
#include <hip/hip_runtime.h>
#include <hip/hip_bf16.h>

// DotProductNonLocalBlock: B=8, C=512, N=3136 (pad 3200), E=256.
// No softmax => fully associative. Factored with DATA-INDEPENDENT
// P = wo·wv, Qt = wq^T·wk, u = wo·bv, r = bk^T·wq, w = Wk^T·bq, κ = bk·bq:
//   G  = X·X^T   [bf16 MFMA, split-K=2 col-interleaved partials, SYMMETRIC:
//                 only upper-triangular tile pairs computed, mirrored on store]
//   T  = Pd·Gp2 (K=1024 folds the reduce)
//   A2 = [T·Q + u·(Qt s)^T + (P s)·r^T]/N + u·r^T
//   a2 = [T·w + u·(s·w) + (P s)·κ]/N + u·κ + bo
//   Out = A2·X + a2 + X
// All MFMA grids put batch in blockIdx.x (XCD affinity: per-batch slices fit 4MB L2
// — round-6 verified: FETCH 144->53MB on the final GEMM).

typedef __attribute__((ext_vector_type(8))) __bf16 bf16x8;
typedef __attribute__((ext_vector_type(4))) float floatx4;

struct __align__(8) bh4 { __hip_bfloat16 x, y, z, w; };
struct __align__(16) bh8 { __hip_bfloat16 h[8]; };

__device__ __forceinline__ void load_lds16(const void* g, void* l) {
    __builtin_amdgcn_global_load_lds((const __attribute__((address_space(1))) void*)g,
                                     (__attribute__((address_space(3))) void*)l, 16, 0, 0);
}

// ---- fused data-independent precompute ----
// z=0: Pd=[P|P] (bf16 512x1024, P=wo·wv).  z=1: Qt (bf16 512x512, wq^T·wk).
// z=2: blocks 0,1 -> u/r/w/kap vectors; block 2 -> zero s accumulator.
__global__ __launch_bounds__(256)
void prep_all(const float* __restrict__ wo, const float* __restrict__ wv,
              const float* __restrict__ wq, const float* __restrict__ wk,
              const float* __restrict__ bq, const float* __restrict__ bk,
              const float* __restrict__ bv,
              __hip_bfloat16* __restrict__ Pdb, __hip_bfloat16* __restrict__ Qtb,
              float* __restrict__ u, float* __restrict__ r, float* __restrict__ w,
              float* __restrict__ kap, float* __restrict__ sv)
{
    const int tid = threadIdx.x;
    if (blockIdx.z == 2) {
        int blk = blockIdx.y * 8 + blockIdx.x;
        if (blk < 2) {
            int c = blk * 256 + tid;
            float su = 0.f, sr = 0.f, sw = 0.f;
            for (int e = 0; e < 256; ++e) {
                su = fmaf(wo[(long long)c * 256 + e], bv[e], su);
                sr = fmaf(bk[e], wq[(long long)e * 512 + c], sr);
                sw = fmaf(wk[(long long)e * 512 + c], bq[e], sw);
            }
            u[c] = su; r[c] = sr; w[c] = sw;
            if (c == 0) {
                float k2 = 0.f;
                for (int e = 0; e < 256; ++e) k2 = fmaf(bk[e], bq[e], k2);
                *kap = k2;
            }
        } else if (blk == 2) {
            float4* p = (float4*)sv;
            for (int i = tid; i < 1024; i += 256) p[i] = make_float4(0.f, 0.f, 0.f, 0.f);
        }
        return;
    }
    __shared__ __align__(16) float As[16][68];
    __shared__ __align__(16) float Bs[16][68];
    const int tx = tid & 15, ty = tid >> 4;
    const int m0 = blockIdx.y * 64, n0 = blockIdx.x * 64;
    const bool doQ = (blockIdx.z == 1);
    const int lk = tid >> 4, lc = (tid & 15) * 4;
    const int lr = tid >> 2, lk4 = (tid & 3) * 4;
    float acc[4][4] = {};
    for (int k0 = 0; k0 < 256; k0 += 16) {
        float4 av, bv4;
        if (doQ) {
            av = *(const float4*)&wq[(long long)(k0 + lk) * 512 + m0 + lc];
            bv4 = *(const float4*)&wk[(long long)(k0 + lk) * 512 + n0 + lc];
        } else {
            av = *(const float4*)&wo[(long long)(m0 + lr) * 256 + k0 + lk4];
            bv4 = *(const float4*)&wv[(long long)(k0 + lk) * 512 + n0 + lc];
        }
        __syncthreads();
        if (doQ) {
            *(float4*)&As[lk][lc] = av;
        } else {
            As[lk4 + 0][lr] = av.x; As[lk4 + 1][lr] = av.y;
            As[lk4 + 2][lr] = av.z; As[lk4 + 3][lr] = av.w;
        }
        *(float4*)&Bs[lk][lc] = bv4;
        __syncthreads();
#pragma unroll
        for (int kk = 0; kk < 16; ++kk) {
            float a[4], b[4];
#pragma unroll
            for (int i = 0; i < 4; ++i) { a[i] = As[kk][ty * 4 + i]; b[i] = Bs[kk][tx * 4 + i]; }
#pragma unroll
            for (int i = 0; i < 4; ++i)
#pragma unroll
                for (int j = 0; j < 4; ++j) acc[i][j] = fmaf(a[i], b[j], acc[i][j]);
        }
    }
    const int mo = m0 + ty * 4, no = n0 + tx * 4;
    if (doQ) {
#pragma unroll
        for (int i = 0; i < 4; ++i)
#pragma unroll
            for (int j = 0; j < 4; ++j)
                Qtb[(long long)(mo + i) * 512 + no + j] = __float2bfloat16(acc[i][j]);
    } else {
#pragma unroll
        for (int i = 0; i < 4; ++i)
#pragma unroll
            for (int j = 0; j < 4; ++j) {
                __hip_bfloat16 v = __float2bfloat16(acc[i][j]);
                Pdb[(long long)(mo + i) * 1024 + no + j] = v;
                Pdb[(long long)(mo + i) * 1024 + no + j + 512] = v;
            }
    }
}

// x [b][512][3136] fp32 -> xT [b][3200][512] bf16 (pad rows zero)
//                        + xnp [b][512][3200] bf16 (pad cols zero)
//                        + s[b][c] += rowsums (atomic)
// All global stores are 16B (bh8); LDS round-trip for the transpose.
__global__ __launch_bounds__(256)
void transpose_conv(const float* __restrict__ x, __hip_bfloat16* __restrict__ xT,
                    __hip_bfloat16* __restrict__ xnp, float* __restrict__ s)
{
    __shared__ float t[64][65];
    const int b = blockIdx.z;
    const int n0 = blockIdx.x * 64, c0 = blockIdx.y * 64;
    const int tid = threadIdx.x;
    const int nch = tid & 7;      // 8-wide chunk index
    const int cr  = tid >> 3;     // 0..31 row-within-pass
    __hip_bfloat16* xTo = xT + (long long)b * 3200 * 512;
    __hip_bfloat16* xno = xnp + (long long)b * 512 * 3200;

    if (n0 >= 3136) {             // pad tile
        bh8 z8;
#pragma unroll
        for (int k = 0; k < 8; ++k) z8.h[k] = __float2bfloat16(0.f);
#pragma unroll
        for (int pass = 0; pass < 2; ++pass) {
            int rr = cr + 32 * pass;
            *(bh8*)&xno[(long long)(c0 + rr) * 3200 + n0 + nch * 8] = z8;
            *(bh8*)&xTo[(long long)(n0 + rr) * 512 + c0 + nch * 8] = z8;
        }
        return;
    }
    const float* xb = x + (long long)b * 512 * 3136;
#pragma unroll
    for (int pass = 0; pass < 2; ++pass) {
        const int cl = cr + 32 * pass;
        const int c = c0 + cl;
        const float* xr = xb + (long long)c * 3136 + n0 + nch * 8;
        float4 v0 = *(const float4*)xr;
        float4 v1 = *(const float4*)(xr + 4);
        bh8 o;
        o.h[0] = __float2bfloat16(v0.x); o.h[1] = __float2bfloat16(v0.y);
        o.h[2] = __float2bfloat16(v0.z); o.h[3] = __float2bfloat16(v0.w);
        o.h[4] = __float2bfloat16(v1.x); o.h[5] = __float2bfloat16(v1.y);
        o.h[6] = __float2bfloat16(v1.z); o.h[7] = __float2bfloat16(v1.w);
        *(bh8*)&xno[(long long)c * 3200 + n0 + nch * 8] = o;
        const int nl = nch * 8;
        t[nl + 0][cl] = v0.x; t[nl + 1][cl] = v0.y;
        t[nl + 2][cl] = v0.z; t[nl + 3][cl] = v0.w;
        t[nl + 4][cl] = v1.x; t[nl + 5][cl] = v1.y;
        t[nl + 6][cl] = v1.z; t[nl + 7][cl] = v1.w;
        float rs = v0.x + v0.y + v0.z + v0.w + v1.x + v1.y + v1.z + v1.w;
        rs += __shfl_xor(rs, 1, 8);
        rs += __shfl_xor(rs, 2, 8);
        rs += __shfl_xor(rs, 4, 8);
        if (nch == 0) atomicAdd(&s[b * 512 + c], rs);
    }
    __syncthreads();
#pragma unroll
    for (int pass = 0; pass < 2; ++pass) {
        const int nl = cr + 32 * pass;
        const int cc = nch * 8;
        bh8 o;
#pragma unroll
        for (int k = 0; k < 8; ++k) o.h[k] = __float2bfloat16(t[nl][cc + k]);
        *(bh8*)&xTo[(long long)(n0 + nl) * 512 + c0 + cc] = o;
    }
}

// Wave-per-output: ps = P·s, sq = Qt·s, a2 = [T·w + u(s·w) + ps·κ]/N + uκ + bo.
__global__ __launch_bounds__(256)
void vec2_kernel(const __hip_bfloat16* __restrict__ T, const __hip_bfloat16* __restrict__ Pdb,
                 const __hip_bfloat16* __restrict__ Qtb, const float* __restrict__ s,
                 const float* __restrict__ u, const float* __restrict__ w,
                 const float* __restrict__ kap, const float* __restrict__ bo,
                 float* __restrict__ ps, float* __restrict__ sq, float* __restrict__ a2)
{
    const int idx = blockIdx.x * 4 + (threadIdx.x >> 6);   // b*512+c
    const int lane = threadIdx.x & 63;
    const int b = idx >> 9, c = idx & 511;
    const int j0 = lane * 8;
    const float* sb = s + b * 512;
    float4 s0 = *(const float4*)&sb[j0], s1 = *(const float4*)&sb[j0 + 4];
    float4 w0 = *(const float4*)&w[j0],  w1 = *(const float4*)&w[j0 + 4];
    bf16x8 pv = *(const bf16x8*)&Pdb[(long long)c * 1024 + j0];
    bf16x8 qv = *(const bf16x8*)&Qtb[(long long)c * 512 + j0];
    bf16x8 tv = *(const bf16x8*)&T[(long long)b * 262144 + (long long)c * 512 + j0];
    float sj[8] = {s0.x, s0.y, s0.z, s0.w, s1.x, s1.y, s1.z, s1.w};
    float wj[8] = {w0.x, w0.y, w0.z, w0.w, w1.x, w1.y, w1.z, w1.w};
    float aps = 0.f, asq = 0.f, atw = 0.f, asw = 0.f;
#pragma unroll
    for (int t = 0; t < 8; ++t) {
        aps = fmaf((float)pv[t], sj[t], aps);
        asq = fmaf((float)qv[t], sj[t], asq);
        atw = fmaf((float)tv[t], wj[t], atw);
        asw = fmaf(sj[t], wj[t], asw);
    }
#pragma unroll
    for (int m = 1; m < 64; m <<= 1) {
        aps += __shfl_xor(aps, m);
        asq += __shfl_xor(asq, m);
        atw += __shfl_xor(atw, m);
        asw += __shfl_xor(asw, m);
    }
    if (lane == 0) {
        ps[idx] = aps; sq[idx] = asq;
        float kp = *kap;
        a2[idx] = (atw + u[c] * asw + aps * kp) * (1.f / 3136.f) + u[c] * kp + bo[c];
    }
}

#define SWZ64(row) ((row) & 7)

// G GEMM with symmetric mirroring. 64x64 tile, BK=64, operands = xnp (both).
// Grid: x = batch + 8*ks (XCD affinity), y = triangular pair index (36).
// Stores partial ks at column offset ks*512 (each split-K partial of X·X^T is
// itself symmetric -> mirror is exact). Mirror tile written as bh4 8B stores;
// diagonal pairs skip the mirror.
__global__ __launch_bounds__(256)
void mfma_g(const __hip_bfloat16* __restrict__ A, long long sA, int lda,
            __hip_bfloat16* __restrict__ C, long long sC, int ldc,
            int kLen)
{
    constexpr int BKT = 64;
    constexpr int CPR = BKT / 8;
    constexpr int NC = 64 * CPR / 256;
    __shared__ __hip_bfloat16 As[64 * BKT];
    __shared__ __hip_bfloat16 Bs[64 * BKT];
    const int tid = threadIdx.x;
    const int lane = tid & 63;
    const int w = tid >> 6;
    const int wm = (w >> 1) << 5;
    const int wn = (w & 1) << 5;
    const int ln = lane & 15;
    const int hi = lane >> 4;
    const int bx = blockIdx.x;
    const int batch = bx & 7, ks = bx >> 3;
    int p = blockIdx.y, mt = 0;
    while (p >= 8 - mt) { p -= 8 - mt; ++mt; }
    const int nt = mt + p;
    const int m0 = mt << 6, n0 = nt << 6;
    const long long k0 = (long long)ks * kLen;

    const __hip_bfloat16* gA[NC];
    const __hip_bfloat16* gB[NC];
#pragma unroll
    for (int q0 = 0; q0 < NC; ++q0) {
        int q = tid + 256 * q0;
        int row = q / CPR;
        int c = (q % CPR) ^ SWZ64(row);
        gA[q0] = A + batch * sA + (long long)(m0 + row) * lda + k0 + c * 8;
        gB[q0] = A + batch * sA + (long long)(n0 + row) * lda + k0 + c * 8;
    }
    floatx4 acc[2][2] = {};
    const int nK = kLen / BKT;
    for (int kt = 0; kt < nK; ++kt) {
#pragma unroll
        for (int q0 = 0; q0 < NC; ++q0) {
            load_lds16(gA[q0], As + (tid + 256 * q0) * 8);
            load_lds16(gB[q0], Bs + (tid + 256 * q0) * 8);
            gA[q0] += BKT; gB[q0] += BKT;
        }
        __syncthreads();
#pragma unroll
        for (int kk = 0; kk < BKT / 32; ++kk) {
            const int cidx = kk * 4 + hi;
            bf16x8 af[2], bfr[2];
#pragma unroll
            for (int i = 0; i < 2; ++i) {
                int row = wm + i * 16 + ln;
                af[i] = *(const bf16x8*)(As + row * BKT + ((cidx ^ SWZ64(row)) << 3));
            }
#pragma unroll
            for (int j = 0; j < 2; ++j) {
                int row = wn + j * 16 + ln;
                bfr[j] = *(const bf16x8*)(Bs + row * BKT + ((cidx ^ SWZ64(row)) << 3));
            }
#pragma unroll
            for (int i = 0; i < 2; ++i)
#pragma unroll
                for (int j = 0; j < 2; ++j)
                    acc[i][j] = __builtin_amdgcn_mfma_f32_16x16x32_bf16(af[i], bfr[j], acc[i][j], 0, 0, 0);
        }
        __syncthreads();
    }

    // C/D layout: col = lane&15, row = (lane>>4)*4 + r  [m89-verified]
    __hip_bfloat16* Cb = C + batch * sC + ks * 512;
#pragma unroll
    for (int i = 0; i < 2; ++i) {
        int mb = m0 + wm + i * 16 + hi * 4;
#pragma unroll
        for (int j = 0; j < 2; ++j) {
            int nl = n0 + wn + j * 16 + ln;
            bh4 mv;
            mv.x = __float2bfloat16(acc[i][j][0]);
            mv.y = __float2bfloat16(acc[i][j][1]);
            mv.z = __float2bfloat16(acc[i][j][2]);
            mv.w = __float2bfloat16(acc[i][j][3]);
            Cb[(long long)(mb + 0) * ldc + nl] = mv.x;
            Cb[(long long)(mb + 1) * ldc + nl] = mv.y;
            Cb[(long long)(mb + 2) * ldc + nl] = mv.z;
            Cb[(long long)(mb + 3) * ldc + nl] = mv.w;
            if (mt != nt)
                *(bh4*)&Cb[(long long)nl * ldc + mb] = mv;   // mirrored tile
        }
    }
}

// Small MFMA GEMM, 64x64 tile, BK=64, operands K-contiguous.
// Grid: x = batch, y = n-tile, z = m-tile.
// MODE 5: plain bf16 store.
// MODE 6: bf16 store of (acc + u[m]·sq[b][n] + ps[b][m]·r[n])/N + u[m]·r[n].
template<int MODE>
__global__ __launch_bounds__(256)
void mfma_sm(const __hip_bfloat16* __restrict__ A, long long sA, int lda,
             const __hip_bfloat16* __restrict__ B, long long sB, int ldb,
             __hip_bfloat16* __restrict__ C, long long sC, int ldc,
             const float* __restrict__ pu, const float* __restrict__ pr,
             const float* __restrict__ pps, const float* __restrict__ psq,
             int kLen)
{
    constexpr int BKT = 64;
    constexpr int CPR = BKT / 8;
    constexpr int NC = 64 * CPR / 256;
    __shared__ __hip_bfloat16 As[64 * BKT];
    __shared__ __hip_bfloat16 Bs[64 * BKT];
    const int tid = threadIdx.x;
    const int lane = tid & 63;
    const int w = tid >> 6;
    const int wm = (w >> 1) << 5;
    const int wn = (w & 1) << 5;
    const int ln = lane & 15;
    const int hi = lane >> 4;
    const int batch = blockIdx.x;
    const int m0 = blockIdx.z << 6;
    const int n0 = blockIdx.y << 6;

    const __hip_bfloat16* gA[NC];
    const __hip_bfloat16* gB[NC];
#pragma unroll
    for (int q0 = 0; q0 < NC; ++q0) {
        int q = tid + 256 * q0;
        int row = q / CPR;
        int c = (q % CPR) ^ SWZ64(row);
        gA[q0] = A + batch * sA + (long long)(m0 + row) * lda + c * 8;
        gB[q0] = B + batch * sB + (long long)(n0 + row) * ldb + c * 8;
    }
    floatx4 acc[2][2] = {};
    const int nK = kLen / BKT;
    for (int kt = 0; kt < nK; ++kt) {
#pragma unroll
        for (int q0 = 0; q0 < NC; ++q0) {
            load_lds16(gA[q0], As + (tid + 256 * q0) * 8);
            load_lds16(gB[q0], Bs + (tid + 256 * q0) * 8);
            gA[q0] += BKT; gB[q0] += BKT;
        }
        __syncthreads();
#pragma unroll
        for (int kk = 0; kk < BKT / 32; ++kk) {
            const int cidx = kk * 4 + hi;
            bf16x8 af[2], bfr[2];
#pragma unroll
            for (int i = 0; i < 2; ++i) {
                int row = wm + i * 16 + ln;
                af[i] = *(const bf16x8*)(As + row * BKT + ((cidx ^ SWZ64(row)) << 3));
            }
#pragma unroll
            for (int j = 0; j < 2; ++j) {
                int row = wn + j * 16 + ln;
                bfr[j] = *(const bf16x8*)(Bs + row * BKT + ((cidx ^ SWZ64(row)) << 3));
            }
#pragma unroll
            for (int i = 0; i < 2; ++i)
#pragma unroll
                for (int j = 0; j < 2; ++j)
                    acc[i][j] = __builtin_amdgcn_mfma_f32_16x16x32_bf16(af[i], bfr[j], acc[i][j], 0, 0, 0);
        }
        __syncthreads();
    }

    __hip_bfloat16* Cb = C + batch * sC;
#pragma unroll
    for (int i = 0; i < 2; ++i) {
        int mb = m0 + wm + i * 16 + hi * 4;
#pragma unroll
        for (int r = 0; r < 4; ++r) {
#pragma unroll
            for (int j = 0; j < 2; ++j) {
                int nl = n0 + wn + j * 16 + ln;
                float v = acc[i][j][r];
                if (MODE == 6) {
                    float uu = pu[mb + r], rr = pr[nl];
                    v = (v + uu * psq[batch * 512 + nl] + pps[batch * 512 + mb + r] * rr)
                        * (1.f / 3136.f) + uu * rr;
                }
                Cb[(long long)(mb + r) * ldc + nl] = __float2bfloat16(v);
            }
        }
    }
}

// Final MFMA GEMM: 64(M)x128(N) tile, 4 waves (64x32 each), BK=64.
// Grid: x = batch (XCD affinity), y = n-tile (25), z = m-tile (8).
// Residual x prefetched into VGPRs before the K-loop (completes under the
// loop's vmcnt drains -> epilogue has no exposed 900-cyc HBM latency).
__global__ __launch_bounds__(256)
void mfma64(const __hip_bfloat16* __restrict__ A, long long sA, int lda,
            const __hip_bfloat16* __restrict__ B, long long sB, int ldb,
            float* __restrict__ C, long long sC, int ldc,
            const float* __restrict__ bias, int sBias,
            const float* __restrict__ xres, long long sX,
            int kLen, int Nreal)
{
    constexpr int BKT = 64;
    constexpr int CPR = BKT / 8;
    constexpr int NA = 64 * CPR / 256;
    constexpr int NB = 128 * CPR / 256;
    __shared__ __hip_bfloat16 As[64 * BKT];
    __shared__ __hip_bfloat16 Bs[128 * BKT];
    const int tid = threadIdx.x;
    const int lane = tid & 63;
    const int w = tid >> 6;
    const int ln = lane & 15;
    const int hi = lane >> 4;
    const int batch = blockIdx.x;
    const int m0 = blockIdx.z << 6;
    const int n0 = blockIdx.y << 7;

    const __hip_bfloat16* gA[NA];
    const __hip_bfloat16* gB[NB];
#pragma unroll
    for (int q0 = 0; q0 < NA; ++q0) {
        int q = tid + 256 * q0;
        int row = q / CPR;
        int c = (q % CPR) ^ SWZ64(row);
        gA[q0] = A + batch * sA + (long long)(m0 + row) * lda + c * 8;
    }
#pragma unroll
    for (int q0 = 0; q0 < NB; ++q0) {
        int q = tid + 256 * q0;
        int row = q / CPR;
        int c = (q % CPR) ^ SWZ64(row);
        gB[q0] = B + batch * sB + (long long)(n0 + row) * ldb + c * 8;
    }

    // residual prefetch (clamped for the n-pad tail)
    const float* xb = xres + batch * sX;
    float xr[4][4][2];
#pragma unroll
    for (int i = 0; i < 4; ++i)
#pragma unroll
        for (int r = 0; r < 4; ++r)
#pragma unroll
            for (int j = 0; j < 2; ++j) {
                int mb = m0 + i * 16 + hi * 4 + r;
                int nl = n0 + w * 32 + j * 16 + ln;
                int nlc = nl < Nreal ? nl : Nreal - 1;
                xr[i][r][j] = xb[(long long)mb * ldc + nlc];
            }

    floatx4 acc[4][2] = {};
    const int nK = kLen / BKT;
    for (int kt = 0; kt < nK; ++kt) {
#pragma unroll
        for (int q0 = 0; q0 < NA; ++q0) {
            load_lds16(gA[q0], As + (tid + 256 * q0) * 8);
            gA[q0] += BKT;
        }
#pragma unroll
        for (int q0 = 0; q0 < NB; ++q0) {
            load_lds16(gB[q0], Bs + (tid + 256 * q0) * 8);
            gB[q0] += BKT;
        }
        __syncthreads();
#pragma unroll
        for (int kk = 0; kk < BKT / 32; ++kk) {
            const int cidx = kk * 4 + hi;
            bf16x8 af[4], bfr[2];
#pragma unroll
            for (int i = 0; i < 4; ++i) {
                int row = i * 16 + ln;
                af[i] = *(const bf16x8*)(As + row * BKT + ((cidx ^ SWZ64(row)) << 3));
            }
#pragma unroll
            for (int j = 0; j < 2; ++j) {
                int row = w * 32 + j * 16 + ln;
                bfr[j] = *(const bf16x8*)(Bs + row * BKT + ((cidx ^ SWZ64(row)) << 3));
            }
#pragma unroll
            for (int i = 0; i < 4; ++i)
#pragma unroll
                for (int j = 0; j < 2; ++j)
                    acc[i][j] = __builtin_amdgcn_mfma_f32_16x16x32_bf16(af[i], bfr[j], acc[i][j], 0, 0, 0);
        }
        __syncthreads();
    }

    float* Cb = C + batch * sC;
#pragma unroll
    for (int i = 0; i < 4; ++i) {
        int mb = m0 + i * 16 + hi * 4;
#pragma unroll
        for (int r = 0; r < 4; ++r) {
            float bb = bias[batch * sBias + mb + r];
#pragma unroll
            for (int j = 0; j < 2; ++j) {
                int nl = n0 + w * 32 + j * 16 + ln;
                if (nl < Nreal) {
                    Cb[(long long)(mb + r) * ldc + nl] = acc[i][j][r] + bb + xr[i][r][j];
                }
            }
        }
    }
}

extern "C" void kernel_launch(void* const* d_in, const int* in_sizes, int n_in,
                              void* d_out, int out_size, void* d_ws, size_t ws_size,
                              hipStream_t stream)
{
    const float* x  = (const float*)d_in[0];
    const float* wq = (const float*)d_in[1];
    const float* bq = (const float*)d_in[2];
    const float* wk = (const float*)d_in[3];
    const float* bk = (const float*)d_in[4];
    const float* wv = (const float*)d_in[5];
    const float* bv = (const float*)d_in[6];
    const float* wo = (const float*)d_in[7];
    const float* bo = (const float*)d_in[8];
    float* out = (float*)d_out;

    const int N = 3136;
    const long long xs = 512LL * N;               // 1,605,632
    const long long xs2 = 512LL * 3200;           // xnp per-batch stride

    // d_out scratch (51.4 MB), all dead before the final GEMM writes out:
    char* ob = (char*)d_out;
    __hip_bfloat16* xnp = (__hip_bfloat16*)ob;                 // @0: 26,214,400 (dead after G)
    __hip_bfloat16* Gp2 = (__hip_bfloat16*)(ob + 26214400);    // 8x512x1024 bf16 = 8,388,608
    __hip_bfloat16* Tb  = (__hip_bfloat16*)(ob + 34603008);    // 8x512x512 bf16 = 4,194,304

    // ws (~32.05 MB). Final GEMM reads only ws + x.
    char* wsb = (char*)d_ws;
    __hip_bfloat16* xT  = (__hip_bfloat16*)wsb;                // 26,214,400
    __hip_bfloat16* A2b = (__hip_bfloat16*)(wsb + 26214400);   //  4,194,304
    __hip_bfloat16* Pdb = (__hip_bfloat16*)(wsb + 30408704);   //  1,048,576
    __hip_bfloat16* Qtb = (__hip_bfloat16*)(wsb + 31457280);   //    524,288
    float* sv  = (float*)(wsb + 31981568);                     //     16,384
    float* u_  = (float*)(wsb + 31997952);                     //      2,048
    float* r_  = (float*)(wsb + 32000000);                     //      2,048
    float* w_  = (float*)(wsb + 32002048);                     //      2,048
    float* kap = (float*)(wsb + 32004096);                     //         16
    float* ps  = (float*)(wsb + 32004112);                     //     16,384
    float* sq  = (float*)(wsb + 32020496);                     //     16,384
    float* a2v = (float*)(wsb + 32036880);                     //     16,384

    // 1) fused data-independent precompute (P/Qt/u/r/w/kap + zero s)
    prep_all<<<dim3(8, 8, 3), 256, 0, stream>>>(wo, wv, wq, wk, bq, bk, bv,
                                                Pdb, Qtb, u_, r_, w_, kap, sv);

    // 2) xT + xnp + s (16B stores)
    transpose_conv<<<dim3(50, 8, 8), 256, 0, stream>>>(x, xT, xnp, sv);

    // 3) Gp2 = partials of X·X^T  (split-K=2, K=1600, BK=64), symmetric:
    //    36 upper-tri tile pairs x 16 (batch,ks) = 576 blocks, mirror on store
    mfma_g<<<dim3(16, 36), 256, 0, stream>>>(
        xnp, xs2, 3200, Gp2, 524288, 1024, 1600);

    // 4) T = Pd·Gp2  (K=1024 folds the split-K reduce)
    mfma_sm<5><<<dim3(8, 8, 8), 256, 0, stream>>>(
        Pdb, 0, 1024, Gp2, 524288, 1024, Tb, 262144, 512,
        nullptr, nullptr, nullptr, nullptr, 1024);

    // 5) ps = P·s, sq = Qt·s, a2 = [T·w + u(s·w) + ps·κ]/N + uκ + bo
    vec2_kernel<<<1024, 256, 0, stream>>>(Tb, Pdb, Qtb, sv, u_, w_, kap, bo, ps, sq, a2v);

    // 6) A2 = [T·Q + u·sq^T + ps·r^T]/N + u·r^T  -> bf16
    mfma_sm<6><<<dim3(8, 8, 8), 256, 0, stream>>>(
        Tb, 262144, 512, Qtb, 0, 512, A2b, 262144, 512,
        u_, r_, ps, sq, 512);

    // 7) out = A2·X + a2 + x   (M=512, N=3136, K=512)
    mfma64<<<dim3(8, 25, 8), 256, 0, stream>>>(
        A2b, 262144, 512, xT, 3200LL * 512, 512,
        out, xs, N, a2v, 512, x, xs, 512, N);
}